// Round 2
// baseline (248.409 us; speedup 1.0000x reference)
//
#include <hip/hip_runtime.h>
#include <math.h>
#include <stdint.h>

// Problem constants (B=4, S=4096, D=2048, E=64, K=8)
#define NTOK   16384      // B*S
#define DDIM   2048
#define NE     64
#define TOPK   8

#define THREADS 512
#define TOKPB   16        // tokens per block -> 1024 blocks -> 3 resident/CU
#define BK      64        // K-chunk per stage
#define NCHUNK  (DDIM / BK)   // 32

// float4 slots: x tile [16 t][16 k4] (4 KiB), W tile [64 k][16 e4] (16 KiB)
#define XSLOTS   (TOKPB * (BK / 4))   // 256
#define WSLOTS   (BK * (NE / 4))      // 1024
#define BUFSLOTS (XSLOTS + WSLOTS)    // 1280 (20 KiB)
#define SMEMF4   (2 * BUFSLOTS)       // 2560 f4 = 40 KiB -> 3 blocks/CU

// Async global->LDS DMA, 16 B per lane. LDS dest is wave-uniform base +
// lane*16 (m104/m108); all layouts here are LINEAR on both sides (no
// swizzle needed -- see bank analysis in comments below).
__device__ __forceinline__ void gl_lds16(const void* g, void* l) {
    __builtin_amdgcn_global_load_lds(
        (const __attribute__((address_space(1))) void*)(uintptr_t)g,
        (__attribute__((address_space(3))) void*)(uintptr_t)l,
        16, 0, 0);
}

__global__ __launch_bounds__(THREADS, 6) void gate_kernel(
    const float* __restrict__ x, const float* __restrict__ W,
    const float* __restrict__ b, float* __restrict__ out)
{
    __shared__ float4 smem[SMEMF4];   // 40 KiB

    const int tid  = threadIdx.x;
    const int wave = tid >> 6;
    const int lane = tid & 63;
    const int ks   = tid >> 5;        // k-quad slice 0..15 (4 k per chunk)
    const int tg   = (tid >> 4) & 1;  // token group (8 tokens each)
    const int eg   = tid & 15;        // expert quad (4 experts each)
    const int tok0 = blockIdx.x * TOKPB;

    // ---- staging sources (fully linear, fully coalesced) ----
    // x tile: slot s = wave*64+lane (waves 0..3): t = s>>4, k4 = s&15
    //   -> 16 lanes cover one token's 256 B run.
    const float* gx  = x + (size_t)(tok0 + wave * 4 + (lane >> 4)) * DDIM
                         + (lane & 15) * 4;
    // W tile: slot s = wave*128 + d*64 + lane: k = s>>4, e4 = s&15
    //   -> row-major [k][e4], matches global exactly.
    const float* gw0 = W + (size_t)(wave * 8 + (lane >> 4)) * NE + (lane & 15) * 4;
    const float* gw1 = gw0 + (size_t)4 * NE;

    auto stage = [&](int c) {
        float4* Bf = &smem[(c & 1) * BUFSLOTS];
        const int kc = c * BK;
        if (wave < 4) gl_lds16(gx + kc, &Bf[wave * 64]);          // x: 4 KiB
        gl_lds16(gw0 + (size_t)kc * NE, &Bf[XSLOTS + wave * 128]);        // W lo
        gl_lds16(gw1 + (size_t)kc * NE, &Bf[XSLOTS + wave * 128 + 64]);   // W hi
    };

    float acc[8][4];
#pragma unroll
    for (int i = 0; i < 8; ++i)
#pragma unroll
        for (int m = 0; m < 4; ++m) acc[i][m] = 0.f;

    // Per chunk per thread: 4 W-b128 + 8 x-b128 feed 128 FMAs.
    // Bank behavior: x read slot (tg*8+i)*16+ks -> quad ks&7, 16 eg-lanes
    // broadcast (free), tg 2-way alias (free). W read slot k*16+eg ->
    // quad eg&7, 32 distinct addrs = 512 B unique -> inherent 4 cycles
    // (bandwidth-optimal, uniform per quad). No swizzle needed anywhere.
    auto compute = [&](int c) {
        const float4* BX = &smem[(c & 1) * BUFSLOTS];
        const float4* BW = BX + XSLOTS;
        float4 wreg[4];
#pragma unroll
        for (int kk = 0; kk < 4; ++kk)
            wreg[kk] = BW[(ks * 4 + kk) * 16 + eg];
#pragma unroll
        for (int i = 0; i < 8; ++i) {
            const float4 xv = BX[(tg * 8 + i) * 16 + ks];
            const float* xp = (const float*)&xv;
#pragma unroll
            for (int kk = 0; kk < 4; ++kk) {
                const float xs = xp[kk];
                const float* wp = (const float*)&wreg[kk];
#pragma unroll
                for (int m = 0; m < 4; ++m)
                    acc[i][m] = fmaf(xs, wp[m], acc[i][m]);
            }
        }
    };

    // ---- 2-buffer pipeline: sync (drains vmcnt) -> stage next -> compute.
    // stage(c+1) completes during compute(c) (~2-3k cyc >> 900 cyc HBM);
    // 3 independent barrier domains/CU fill the residual stalls.
    stage(0);
#pragma unroll 1
    for (int c = 0; c < NCHUNK; ++c) {
        __syncthreads();                   // all stage(c) done; buf (c+1)&1 free
        if (c + 1 < NCHUNK) stage(c + 1);
        __builtin_amdgcn_s_setprio(1);
        compute(c);
        __builtin_amdgcn_s_setprio(0);
    }
    __syncthreads();   // drain + all compute done; smem reusable

    // ---- reduce the ks pair (lanes l, l^32 share (tg,eg)) ----
#pragma unroll
    for (int i = 0; i < 8; ++i)
#pragma unroll
        for (int m = 0; m < 4; ++m)
            acc[i][m] += __shfl_xor(acc[i][m], 32);

    // ---- cross-wave partials: [8 w][32 p][9 f4] = 2304 f4 (36 KiB) ----
    float4* part4 = (float4*)smem;
    const int p = lane & 31;              // = tg*16 + eg
    if (lane < 32) {
        float4* dst = part4 + (wave * 32 + p) * 9;
#pragma unroll
        for (int i = 0; i < 8; ++i)
            dst[i] = make_float4(acc[i][0], acc[i][1], acc[i][2], acc[i][3]);
    }
    __syncthreads();

    float* out_g   = out;                           // [16384][8]
    float* out_idx = out + (size_t)NTOK * TOPK;     // [16384][8] (as float)
    float* out_s   = out + (size_t)NTOK * TOPK * 2; // [16384][64]

    // ---- collect 8 wave-partials, bias, sigmoid (threads 0..255) ----
    const int t  = tid >> 4;              // token 0..15
    const int e4 = tid & 15;              // expert quad
    float4 sg = make_float4(0.f, 0.f, 0.f, 0.f);
    if (tid < 256) {
        const int cp = ((t >> 3) << 4) + e4;   // partial lane = tg*16 + eg
        const int cf = t & 7;                  // f4 index = i
        float sx = 0.f, sy = 0.f, sz = 0.f, sw = 0.f;
#pragma unroll
        for (int w = 0; w < 8; ++w) {
            const float4 v = part4[(w * 32 + cp) * 9 + cf];
            sx += v.x; sy += v.y; sz += v.z; sw += v.w;
        }
        const float4 bv = *(const float4*)(b + e4 * 4);
        sg.x = 1.f / (1.f + expf(-(sx + bv.x)));
        sg.y = 1.f / (1.f + expf(-(sy + bv.y)));
        sg.z = 1.f / (1.f + expf(-(sz + bv.z)));
        sg.w = 1.f / (1.f + expf(-(sw + bv.w)));
    }
    __syncthreads();   // partial reads done before score overwrite

    float4* sc4 = (float4*)smem;          // scores [16 t][17 f4]
    if (tid < 256) {
        *(float4*)(out_s + (size_t)(tok0 + t) * NE + e4 * 4) = sg;  // coalesced
        sc4[t * 17 + e4] = sg;
    }
    __syncthreads();

    // ---- parallel top-8: 8 lanes per token, butterfly argmax with
    // lowest-index tie-break (matches jax.lax.top_k) ----
    if (tid < 128) {
        const int tt = tid >> 3, lg = tid & 7;
        const float4 a0 = sc4[tt * 17 + lg * 2];
        const float4 a1 = sc4[tt * 17 + lg * 2 + 1];
        float s[8] = {a0.x, a0.y, a0.z, a0.w, a1.x, a1.y, a1.z, a1.w};
        float vsel = 0.f; int esel = 0; float ssum = 0.f;
#pragma unroll
        for (int j = 0; j < TOPK; ++j) {
            // local max over remaining 8 (ascending scan, strict > -> lowest idx)
            float bvv = s[0]; int be = 0;
#pragma unroll
            for (int m = 1; m < 8; ++m)
                if (s[m] > bvv) { bvv = s[m]; be = m; }
            float v = bvv; int ec = lg * 8 + be;
#pragma unroll
            for (int d = 1; d < 8; d <<= 1) {
                const float ov = __shfl_xor(v, d);
                const int   oe = __shfl_xor(ec, d);
                if (ov > v || (ov == v && oe < ec)) { v = ov; ec = oe; }
            }
            ssum += v;
            if (lg == j) { vsel = v; esel = ec; }
            // remove winner (static indexing only -- rule #20)
            if ((ec >> 3) == lg) {
                const int sl = ec & 7;
#pragma unroll
                for (int m = 0; m < 8; ++m)
                    if (sl == m) s[m] = -1.f;   // sigmoid in (0,1) -> excluded
            }
        }
        const float inv = 1.f / ssum;
        out_g  [(size_t)(tok0 + tt) * TOPK + lg] = vsel * inv;
        out_idx[(size_t)(tok0 + tt) * TOPK + lg] = (float)esel;
    }
}

extern "C" void kernel_launch(void* const* d_in, const int* in_sizes, int n_in,
                              void* d_out, int out_size, void* d_ws, size_t ws_size,
                              hipStream_t stream) {
    const float* x = (const float*)d_in[0];
    const float* W = (const float*)d_in[1];
    const float* b = (const float*)d_in[2];
    // d_in[3] is k (==8), compile-time constant here.
    float* out = (float*)d_out;
    gate_kernel<<<NTOK / TOKPB, THREADS, 0, stream>>>(x, W, b, out);
}

// Round 3
// 234.493 us; speedup vs baseline: 1.0593x; 1.0593x over previous
//
#include <hip/hip_runtime.h>
#include <math.h>
#include <stdint.h>

// Problem constants (B=4, S=4096, D=2048, E=64, K=8)
#define NTOK   16384      // B*S
#define DDIM   2048
#define NE     64
#define TOPK   8

#define THREADS 256
#define TOKPB   16        // tokens per block -> 1024 blocks -> 4 resident/CU
#define BK      64        // K-chunk per stage
#define NCHUNK  (DDIM / BK)   // 32

// x tile per buffer: [16 t][16 k4] = 256 f4 (4 KiB). Two buffers = 512 f4.
// Epilogue partials: [4 w][16 p][17 f4] = 1088 f4 (17 KiB) -> LDS decl 1088.
#define XSLOTS 256

// Async global->LDS DMA, 16 B per lane. LDS dest is wave-uniform base +
// lane*16 (m104/m108). x layout is LINEAR both sides; compute reads are
// 2-way bank aliased max (free, m136) because the bank quad is driven by
// ks (4 distinct per wave) and only tg (2 values) aliases.
__device__ __forceinline__ void gl_lds16(const void* g, void* l) {
    __builtin_amdgcn_global_load_lds(
        (const __attribute__((address_space(1))) void*)(uintptr_t)g,
        (__attribute__((address_space(3))) void*)(uintptr_t)l,
        16, 0, 0);
}

__global__ __launch_bounds__(THREADS, 4) void gate_kernel(
    const float* __restrict__ x, const float* __restrict__ W,
    const float* __restrict__ b, float* __restrict__ out)
{
    __shared__ float4 smem[1088];   // 17 KiB -> 4 blocks/CU easily

    const int tid  = threadIdx.x;
    const int wave = tid >> 6;
    const int lane = tid & 63;
    const int ks   = tid >> 4;        // k-slice 0..15 (4 k per chunk each)
    const int tg   = (tid >> 3) & 1;  // token group (8 tokens each)
    const int eg   = tid & 7;         // expert octet (8 experts each)
    const int tok0 = blockIdx.x * TOKPB;

    // x staging: wave issues ONE gl_lds16 per chunk; slot s = wave*64+lane
    //   -> t = s>>4, k4 = s&15. Source: 4 token rows x 256 B, coalesced.
    const float* gx = x + (size_t)(tok0 + wave * 4 + (lane >> 4)) * DDIM
                        + (lane & 15) * 4;
    // W register loads: rows k = c*64 + ks*4 + kk, cols eg*8 .. eg*8+7.
    // Per-chunk slice is 16 KB -> L1-resident across the CU's 4 blocks.
    const float* gw = W + (size_t)(ks * 4) * NE + eg * 8;

    auto stage = [&](int c) {
        gl_lds16(gx + c * BK, &smem[(c & 1) * XSLOTS + wave * 64]);
    };

    float acc[8][8];
#pragma unroll
    for (int i = 0; i < 8; ++i)
#pragma unroll
        for (int j = 0; j < 8; ++j) acc[i][j] = 0.f;

    stage(0);
#pragma unroll 1
    for (int c = 0; c < NCHUNK; ++c) {
        __syncthreads();   // stage(c) drained & visible (compiler vmcnt(0))

        // W loads FIRST (older than the stage DMA below): compiler waitcnts
        // before the FMAs then leave stage(c+1) in flight (in-order vmcnt).
        const float* wb = gw + (size_t)(c * BK) * NE;
        float4 wv[4][2];
#pragma unroll
        for (int kk = 0; kk < 4; ++kk) {
            wv[kk][0] = *(const float4*)(wb + kk * NE);
            wv[kk][1] = *(const float4*)(wb + kk * NE + 4);
        }
        __builtin_amdgcn_sched_barrier(0);   // pin W-loads before stage DMA
        if (c + 1 < NCHUNK) stage(c + 1);    // lands during compute (~2k cyc)

        const float4* BX = &smem[(c & 1) * XSLOTS];
#pragma unroll
        for (int i = 0; i < 8; ++i) {
            const float4 xv = BX[(tg * 8 + i) * 16 + ks];   // 2-way max, free
            const float* xp = (const float*)&xv;
#pragma unroll
            for (int kk = 0; kk < 4; ++kk) {
                const float xs = xp[kk];
                const float* w0 = (const float*)&wv[kk][0];
                const float* w1 = (const float*)&wv[kk][1];
#pragma unroll
                for (int m = 0; m < 4; ++m) {
                    acc[i][m]     = fmaf(xs, w0[m], acc[i][m]);
                    acc[i][4 + m] = fmaf(xs, w1[m], acc[i][4 + m]);
                }
            }
        }
    }
    __syncthreads();   // last compute done; smem reusable for epilogue

    // ---- reduce over ks within wave: lanes l, l^16, l^32, l^48 share
    // p = tid&15 = (tg,eg) and cover the wave's 4 ks slices ----
#pragma unroll
    for (int i = 0; i < 8; ++i)
#pragma unroll
        for (int j = 0; j < 8; ++j) {
            acc[i][j] += __shfl_xor(acc[i][j], 16);
            acc[i][j] += __shfl_xor(acc[i][j], 32);
        }

    // ---- cross-wave partials: [4 w][16 p][17 f4 pad] ----
    float4* part4 = smem;
    if (lane < 16) {
        float4* dst = part4 + (wave * 16 + lane) * 17;
#pragma unroll
        for (int i = 0; i < 8; ++i) {
            dst[i * 2]     = make_float4(acc[i][0], acc[i][1], acc[i][2], acc[i][3]);
            dst[i * 2 + 1] = make_float4(acc[i][4], acc[i][5], acc[i][6], acc[i][7]);
        }
    }
    __syncthreads();

    float* out_g   = out;                           // [16384][8]
    float* out_idx = out + (size_t)NTOK * TOPK;     // [16384][8] (as float)
    float* out_s   = out + (size_t)NTOK * TOPK * 2; // [16384][64]

    // ---- collect 4 wave-partials, bias, sigmoid (all 256 threads) ----
    const int t   = tid >> 4;           // token 0..15
    const int e4  = tid & 15;           // expert quad
    const int tg2 = t >> 3, i2 = t & 7;
    const int eg2 = e4 >> 1, h2 = e4 & 1;
    float4 sum = make_float4(0.f, 0.f, 0.f, 0.f);
#pragma unroll
    for (int w = 0; w < 4; ++w) {
        const float4 v = part4[(w * 16 + tg2 * 8 + eg2) * 17 + i2 * 2 + h2];
        sum.x += v.x; sum.y += v.y; sum.z += v.z; sum.w += v.w;
    }
    const float4 bv = *(const float4*)(b + e4 * 4);
    float4 sg;
    sg.x = 1.f / (1.f + expf(-(sum.x + bv.x)));
    sg.y = 1.f / (1.f + expf(-(sum.y + bv.y)));
    sg.z = 1.f / (1.f + expf(-(sum.z + bv.z)));
    sg.w = 1.f / (1.f + expf(-(sum.w + bv.w)));
    __syncthreads();   // all partial reads done before score overwrite

    float4* sc4 = smem;                 // scores [16 t][17 f4]
    sc4[t * 17 + e4] = sg;
    *(float4*)(out_s + (size_t)(tok0 + t) * NE + e4 * 4) = sg;   // coalesced
    __syncthreads();

    // ---- parallel top-8: 8 lanes per token, butterfly argmax with
    // lowest-index tie-break (matches jax.lax.top_k) ----
    if (tid < 128) {
        const int tt = tid >> 3, lg = tid & 7;
        const float4 a0 = sc4[tt * 17 + lg * 2];
        const float4 a1 = sc4[tt * 17 + lg * 2 + 1];
        float s[8] = {a0.x, a0.y, a0.z, a0.w, a1.x, a1.y, a1.z, a1.w};
        float vsel = 0.f; int esel = 0; float ssum = 0.f;
#pragma unroll
        for (int j = 0; j < TOPK; ++j) {
            // local max over remaining 8 (ascending scan, strict > -> lowest idx)
            float bvv = s[0]; int be = 0;
#pragma unroll
            for (int m = 1; m < 8; ++m)
                if (s[m] > bvv) { bvv = s[m]; be = m; }
            float v = bvv; int ec = lg * 8 + be;
#pragma unroll
            for (int d = 1; d < 8; d <<= 1) {
                const float ov = __shfl_xor(v, d);
                const int   oe = __shfl_xor(ec, d);
                if (ov > v || (ov == v && oe < ec)) { v = ov; ec = oe; }
            }
            ssum += v;
            if (lg == j) { vsel = v; esel = ec; }
            // remove winner (static indexing only -- rule #20)
            if ((ec >> 3) == lg) {
                const int sl = ec & 7;
#pragma unroll
                for (int m = 0; m < 8; ++m)
                    if (sl == m) s[m] = -1.f;   // sigmoid in (0,1) -> excluded
            }
        }
        const float inv = 1.f / ssum;
        out_g  [(size_t)(tok0 + tt) * TOPK + lg] = vsel * inv;
        out_idx[(size_t)(tok0 + tt) * TOPK + lg] = (float)esel;
    }
}

extern "C" void kernel_launch(void* const* d_in, const int* in_sizes, int n_in,
                              void* d_out, int out_size, void* d_ws, size_t ws_size,
                              hipStream_t stream) {
    const float* x = (const float*)d_in[0];
    const float* W = (const float*)d_in[1];
    const float* b = (const float*)d_in[2];
    // d_in[3] is k (==8), compile-time constant here.
    float* out = (float*)d_out;
    gate_kernel<<<NTOK / TOKPB, THREADS, 0, stream>>>(x, W, b, out);
}